// Round 15
// baseline (211.673 us; speedup 1.0000x reference)
//
#include <hip/hip_runtime.h>

#define B_ 16
#define C_ 128
#define N_ 1024
#define K_ 9
#define NEG_SLOPE 0.2f
#define BN_EPS 1e-5f

typedef __attribute__((ext_vector_type(8))) short short8;
typedef __attribute__((ext_vector_type(4))) float f32x4;
typedef __attribute__((ext_vector_type(4))) unsigned short u16x4;

__device__ __forceinline__ unsigned short f2bf(float f) {
    union { float f; unsigned u; } v; v.f = f;
    unsigned r = v.u + 0x7fffu + ((v.u >> 16) & 1u);   // RNE
    return (unsigned short)(r >> 16);
}
__device__ __forceinline__ float bf2f(unsigned short h) {
    union { unsigned u; float f; } v; v.u = ((unsigned)h) << 16; return v.f;
}

// ------------------------------------------------- featsT[b][n][c] = x[b][c][n]
__global__ __launch_bounds__(256) void k_transpose(const float* __restrict__ x,
                                                   float* __restrict__ featsT)
{
    __shared__ float t[32][33];
    int blk = blockIdx.x;            // B * (C/32) * (N/32) = 2048
    int b = blk / 128;
    int rem = blk % 128;
    int c0 = (rem / 32) * 32;
    int n0 = (rem % 32) * 32;
    int tj = threadIdx.x & 31;
    int ti = threadIdx.x >> 5;
    #pragma unroll
    for (int s = 0; s < 32; s += 8)
        t[ti + s][tj] = x[(b * C_ + c0 + ti + s) * N_ + n0 + tj];
    __syncthreads();
    #pragma unroll
    for (int s = 0; s < 32; s += 8)
        featsT[(b * N_ + n0 + ti + s) * C_ + c0 + tj] = t[tj][ti + s];
}

// ---------------- prep: Bf (hi/lo bf16 fragment-order table) + sq (fp32)
// Bf[chunk*8+j] = hi/lo bf16 of feats[n][kb*32+q*8+j],
// chunk = ((b*8+kb)*64 + (n>>4))*64 + q*16 + (n&15); kb 0..3 hi, 4..7 lo
__global__ __launch_bounds__(256) void k_prep(const float* __restrict__ featsT,
        unsigned short* __restrict__ Bf, float* __restrict__ sq)
{
    int tid = threadIdx.x;
    int lane = tid & 63, wv = tid >> 6;
    int half = lane >> 5;
    int l2 = lane & 31;
    int gp = blockIdx.x * 8 + wv * 2 + half; // global point
    int b = gp >> 10, n = gp & 1023;

    int ch0 = (l2 & 15) * 8;
    const float4* f4 = (const float4*)&featsT[gp * C_ + ch0];
    float4 v0 = f4[0], v1 = f4[1];

    u16x4 o0, o1;
    if (l2 < 16) {
        o0.x = f2bf(v0.x); o0.y = f2bf(v0.y); o0.z = f2bf(v0.z); o0.w = f2bf(v0.w);
        o1.x = f2bf(v1.x); o1.y = f2bf(v1.y); o1.z = f2bf(v1.z); o1.w = f2bf(v1.w);
    } else {
        o0.x = f2bf(v0.x - bf2f(f2bf(v0.x))); o0.y = f2bf(v0.y - bf2f(f2bf(v0.y)));
        o0.z = f2bf(v0.z - bf2f(f2bf(v0.z))); o0.w = f2bf(v0.w - bf2f(f2bf(v0.w)));
        o1.x = f2bf(v1.x - bf2f(f2bf(v1.x))); o1.y = f2bf(v1.y - bf2f(f2bf(v1.y)));
        o1.z = f2bf(v1.z - bf2f(f2bf(v1.z))); o1.w = f2bf(v1.w - bf2f(f2bf(v1.w)));
    }
    long chunk = (((long)(b * 8 + (l2 >> 2)) * 64 + (n >> 4)) << 6) + ((l2 & 3) * 16 + (n & 15));
    *(u16x4*)&Bf[chunk * 8]     = o0;
    *(u16x4*)&Bf[chunk * 8 + 4] = o1;

    float ss = v0.x*v0.x + v0.y*v0.y + v0.z*v0.z + v0.w*v0.w
             + v1.x*v1.x + v1.y*v1.y + v1.z*v1.z + v1.w*v1.w;
    #pragma unroll
    for (int off = 1; off < 16; off <<= 1)
        ss += __shfl_xor(ss, off);
    if (l2 == 0) sq[gp] = ss;
}

// --------------- MFMA KNN: 16 rows x 1024 cols; A-frags direct from Bf,
// r-split 2-phase keybuf (33 KB), (512,6): no spill (R13-verified).
__global__ __launch_bounds__(512, 6) void k_knn(
        const unsigned short* __restrict__ Bf, const float* __restrict__ sq,
        int* __restrict__ idxout)
{
    __shared__ unsigned keybuf[8][1028];
    __shared__ float sqn[16];

    int L = blockIdx.x;                       // 1024 = 16 b * 64 tiles
    int xcd = L & 7, slot = L >> 3;
    int b = xcd * 2 + (slot >> 6);
    int tile = slot & 63;
    int n0 = tile * 16;
    int tid = threadIdx.x;

    if (tid < 16) sqn[tid] = sq[b * N_ + n0 + tid];
    __syncthreads();

    int wv = tid >> 6, lane = tid & 63, quad = lane >> 4, cl = lane & 15;

    f32x4 acc[8];
    #pragma unroll
    for (int t = 0; t < 8; ++t) acc[t] = (f32x4){0.f, 0.f, 0.f, 0.f};

    const short8* bfp = (const short8*)Bf;
    #pragma unroll
    for (int kb = 0; kb < 4; ++kb) {
        // A-frags for the 16 tile rows, direct from Bf (hi at kb, lo at kb+4)
        long abase = (((long)(b * 8 + kb) * 64 + tile) << 6) + quad * 16 + cl;
        short8 afh = bfp[abase];
        short8 afl = bfp[abase + 16384];      // +4*64*64 chunks
        long bh = (((long)(b * 8 + kb) * 64 + wv * 8) << 6) + lane;
        long bl = bh + 16384;
        #pragma unroll
        for (int t = 0; t < 8; ++t) {         // B-hi: hiA*hiB + loA*hiB
            short8 bfr = bfp[bh + t * 64];
            acc[t] = __builtin_amdgcn_mfma_f32_16x16x32_bf16(afh, bfr, acc[t], 0, 0, 0);
            acc[t] = __builtin_amdgcn_mfma_f32_16x16x32_bf16(afl, bfr, acc[t], 0, 0, 0);
        }
        #pragma unroll
        for (int t = 0; t < 8; ++t) {         // B-lo: hiA*loB
            short8 bfr = bfp[bl + t * 64];
            acc[t] = __builtin_amdgcn_mfma_f32_16x16x32_bf16(afh, bfr, acc[t], 0, 0, 0);
        }
    }

    // convert acc -> monotone u32 keys; r={0,1} staged now, r={2,3} held (16 regs)
    unsigned k0[8][2], k1[8][2];
    #pragma unroll
    for (int t = 0; t < 8; ++t) {
        int col = ((wv * 8 + t) << 4) + cl;
        float sm = sq[b * N_ + col];
        #pragma unroll
        for (int r = 0; r < 4; ++r) {
            float d2 = fmaf(-2.f, acc[t][r], sm + sqn[quad * 4 + r]);
            unsigned bits = __float_as_uint(d2);
            unsigned key = bits ^ ((unsigned)((int)bits >> 31) | 0x80000000u);
            if (r < 2) k0[t][r] = key; else k1[t][r - 2] = key;
        }
    }

    // two phases: ph=0 rows quad*4+{0,1}, ph=1 rows quad*4+{2,3}
    #pragma unroll 1
    for (int ph = 0; ph < 2; ++ph) {
        #pragma unroll
        for (int t = 0; t < 8; ++t) {
            int col = ((wv * 8 + t) << 4) + cl;
            #pragma unroll
            for (int r2 = 0; r2 < 2; ++r2)
                keybuf[quad * 2 + r2][col] = ph ? k1[t][r2] : k0[t][r2];
        }
        __syncthreads();

        int grow = ((wv >> 1) << 2) + ph * 2 + (wv & 1);
        unsigned v[16];
        #pragma unroll
        for (int j = 0; j < 16; ++j)
            v[j] = keybuf[wv][lane + (j << 6)];   // stride-1: conflict-free

        unsigned m = v[0]; int bj = 0;
        #pragma unroll
        for (int j = 1; j < 16; ++j)
            if (v[j] < m) { m = v[j]; bj = j; }   // first j wins ties = smaller col

        #pragma unroll 1
        for (int q = 0; q < K_; ++q) {
            unsigned long long my = ((unsigned long long)m << 10)
                                  | (unsigned)(lane + (bj << 6));
            unsigned long long d = my;
            #pragma unroll
            for (int off = 1; off < 64; off <<= 1) {
                unsigned long long o = __shfl_xor(d, off);
                if (o < d) d = o;
            }
            if (lane == 0)
                idxout[(b * N_ + n0 + grow) * K_ + q] = (int)((unsigned)d & 1023u);
            if (q < K_ - 1 && my == d) {           // unique winner: mask + rescan
                v[bj] = 0xFFFFFFFFu;
                m = v[0]; bj = 0;
                #pragma unroll
                for (int j = 1; j < 16; ++j)
                    if (v[j] < m) { m = v[j]; bj = j; }
            }
        }
        __syncthreads();   // all reads done before next phase overwrites keybuf
    }
}

// ----------------------- prepack W1/W2 into MFMA B-fragment order (bf16)
// wf1 kk0..3 = W1c = W1top - W1bot (for cen@W1c); kk4..7 = W1bot (for nbr@W1bot)
__global__ __launch_bounds__(256) void k_prepack(const float* __restrict__ W1,
        const float* __restrict__ W2, unsigned short* __restrict__ wf1,
        unsigned short* __restrict__ wf2)
{
    int t = blockIdx.x * 256 + threadIdx.x;       // 6144 threads
    if (t < 4096) {                               // W1: kk 0..7
        int kk = t >> 9, wvi = (t >> 6) & 7, lane = t & 63;
        int quad = lane >> 4, col = lane & 15;
        #pragma unroll
        for (int j = 0; j < 8; ++j) {
            int row = kk * 32 + quad * 8 + j;
            float val = W1[row * C_ + 16 * wvi + col];
            if (kk < 4)
                val -= W1[(row + 128) * C_ + 16 * wvi + col];   // W1c
            wf1[t * 8 + j] = f2bf(val);
        }
    } else if (t < 6144) {                        // W2: kk 0..3
        int t2 = t - 4096;
        int kk = t2 >> 9, wvi = (t2 >> 6) & 7, lane = t2 & 63;
        int quad = lane >> 4, col = lane & 15;
        #pragma unroll
        for (int j = 0; j < 8; ++j)
            wf2[t2 * 8 + j] = f2bf(W2[(kk * 32 + quad * 8 + j) * C_ + 16 * wvi + col]);
    }
}

// ------- MFMA edge-MLP + maxpool: block = 8 points, gather-free.
// h1 = leaky(cen@W1c + nbr@W1bot + b1); A-frags direct from Bf hi table.
__global__ __launch_bounds__(512, 4) void k_edge(const unsigned short* __restrict__ Bf,
        const int* __restrict__ idx, const unsigned short* __restrict__ wf1,
        const unsigned short* __restrict__ wf2, const float* __restrict__ b1,
        const float* __restrict__ b2, float* __restrict__ msg)
{
    // LDS: h1 bf16 [80][136] | h2b bf16 [80][136] | ccb bf16 [16][136]  (~48 KB)
    __shared__ __align__(16) char smem[21760 + 21760 + 4352];
    unsigned short* h1  = (unsigned short*)smem;
    unsigned short* h2b = (unsigned short*)(smem + 21760);
    unsigned short* ccb = (unsigned short*)(smem + 43520);
    __shared__ int nb[72];

    int L = blockIdx.x;                 // 2048 = 8 xcd * 256 slots
    int xcd = L & 7, slot = L >> 3;
    int b = xcd * 2 + (slot >> 7);
    int tile8 = slot & 127;
    int n0 = tile8 * 8;
    int tid = threadIdx.x;

    if (tid < 72) nb[tid] = idx[(b * N_ + n0 + tid / 9) * K_ + tid % 9];
    __syncthreads();

    int wv = tid >> 6, lane = tid & 63;
    int quad = lane >> 4, cl = lane & 15;
    const short8* bfp = (const short8*)Bf;
    const short8* w1f = (const short8*)wf1;
    const short8* w2f = (const short8*)wf2;

    // ---- G1a: centers @ W1c + b1 -> ccb (rows 8..15 duplicate rows 0..7)
    {
        float b1v = b1[16 * wv + cl];
        f32x4 a = (f32x4){b1v, b1v, b1v, b1v};
        int n = n0 + (cl & 7);
        #pragma unroll
        for (int kk = 0; kk < 4; ++kk) {
            short8 af = bfp[(((long)(b * 8 + kk) * 64 + (n >> 4)) << 6) + quad * 16 + (n & 15)];
            short8 bf = w1f[(kk * 8 + wv) * 64 + lane];
            a = __builtin_amdgcn_mfma_f32_16x16x32_bf16(af, bf, a, 0, 0, 0);
        }
        #pragma unroll
        for (int r = 0; r < 4; ++r)
            ccb[(quad * 4 + r) * 136 + 16 * wv + cl] = f2bf(a[r]);
    }
    // no barrier: each wave reads back only its own 16 cols of ccb

    // ---- G1b: neighbor rows @ W1bot, + cc[point], leaky -> h1
    #pragma unroll
    for (int t = 0; t < 5; ++t) {
        int row = 16 * t + cl;
        int e = row > 71 ? 71 : row;
        int n = nb[e];
        f32x4 a = (f32x4){0.f, 0.f, 0.f, 0.f};
        #pragma unroll
        for (int kb = 0; kb < 4; ++kb) {
            short8 af = bfp[(((long)(b * 8 + kb) * 64 + (n >> 4)) << 6) + quad * 16 + (n & 15)];
            short8 bf = w1f[((kb + 4) * 8 + wv) * 64 + lane];
            a = __builtin_amdgcn_mfma_f32_16x16x32_bf16(af, bf, a, 0, 0, 0);
        }
        #pragma unroll
        for (int r = 0; r < 4; ++r) {
            int rw = 16 * t + quad * 4 + r;
            int pt = rw / 9; if (pt > 7) pt = 7;
            float v = a[r] + bf2f(ccb[pt * 136 + 16 * wv + cl]);
            v = (v >= 0.f) ? v : NEG_SLOPE * v;
            h1[rw * 136 + 16 * wv + cl] = f2bf(v);
        }
    }
    __syncthreads();

    // ---- GEMM2: h1 @ W2 -> h2b
    #pragma unroll
    for (int t = 0; t < 5; ++t) {
        f32x4 a = (f32x4){0.f, 0.f, 0.f, 0.f};
        #pragma unroll
        for (int kb = 0; kb < 4; ++kb) {
            short8 af = *(const short8*)&h1[(16 * t + cl) * 136 + kb * 32 + quad * 8];
            short8 bf = w2f[(kb * 8 + wv) * 64 + lane];
            a = __builtin_amdgcn_mfma_f32_16x16x32_bf16(af, bf, a, 0, 0, 0);
        }
        #pragma unroll
        for (int r = 0; r < 4; ++r)
            h2b[(16 * t + quad * 4 + r) * 136 + 16 * wv + cl] = f2bf(a[r]);
    }
    __syncthreads();

    // ---- maxpool over 9 edges/point + bias, write msg (B,C,N)
    int p = tid & 7, nb8 = tid >> 3;      // nb8: 0..63
    #pragma unroll
    for (int it = 0; it < 2; ++it) {
        int n = nb8 + 64 * it;
        float m = bf2f(h2b[(p * 9) * 136 + n]);
        #pragma unroll
        for (int q = 1; q < 9; ++q)
            m = fmaxf(m, bf2f(h2b[(p * 9 + q) * 136 + n]));
        msg[(b * C_ + n) * N_ + n0 + p] = m + b2[n];
    }
}

// ---------------------------------------------------- BN statistics per channel
__global__ __launch_bounds__(256) void k_bnstats(const float* __restrict__ msg,
        const float* __restrict__ gamma, const float* __restrict__ beta,
        float* __restrict__ scale, float* __restrict__ shift)
{
    int c = blockIdx.x, tid = threadIdx.x;
    float s = 0.f, ss = 0.f;
    for (int b = 0; b < B_; ++b) {
        const float* row = msg + (b * C_ + c) * N_;
        for (int j = tid; j < N_; j += 256) {
            float v = row[j];
            s += v; ss += v * v;
        }
    }
    __shared__ float rs[256], rss[256];
    rs[tid] = s; rss[tid] = ss;
    __syncthreads();
    for (int off = 128; off > 0; off >>= 1) {
        if (tid < off) { rs[tid] += rs[tid + off]; rss[tid] += rss[tid + off]; }
        __syncthreads();
    }
    if (tid == 0) {
        float mean = rs[0] / (float)(B_ * N_);
        float var = rss[0] / (float)(B_ * N_) - mean * mean;
        float inv = 1.0f / sqrtf(var + BN_EPS);
        float g = gamma[c];
        scale[c] = g * inv;
        shift[c] = beta[c] - g * inv * mean;
    }
}

// ------------------------------------------- BN apply + residual + final ReLU
__global__ __launch_bounds__(256) void k_final(const float* __restrict__ msg,
        const float* __restrict__ x, const float* __restrict__ scale,
        const float* __restrict__ shift, float* __restrict__ out)
{
    int i = blockIdx.x * 256 + threadIdx.x;
    int e = i << 2;
    int c = (e >> 10) & 127;
    float sc = scale[c], sh = shift[c];
    float4 m4 = reinterpret_cast<const float4*>(msg)[i];
    float4 x4 = reinterpret_cast<const float4*>(x)[i];
    float4 o;
    o.x = fmaxf(m4.x * sc + sh + x4.x, 0.f);
    o.y = fmaxf(m4.y * sc + sh + x4.y, 0.f);
    o.z = fmaxf(m4.z * sc + sh + x4.z, 0.f);
    o.w = fmaxf(m4.w * sc + sh + x4.w, 0.f);
    reinterpret_cast<float4*>(out)[i] = o;
}

extern "C" void kernel_launch(void* const* d_in, const int* in_sizes, int n_in,
                              void* d_out, int out_size, void* d_ws, size_t ws_size,
                              hipStream_t stream)
{
    const float* x     = (const float*)d_in[0];
    const float* W1    = (const float*)d_in[1];
    const float* b1    = (const float*)d_in[2];
    const float* W2    = (const float*)d_in[3];
    const float* b2    = (const float*)d_in[4];
    const float* gamma = (const float*)d_in[5];
    const float* beta  = (const float*)d_in[6];
    float* out = (float*)d_out;

    float* ws     = (float*)d_ws;
    float* featsT = ws;                     // 8 MB; dead after k_prep
    float* msg    = ws;                     // aliases featsT (k_edge onward)
    unsigned short* Bf = (unsigned short*)(ws + 2097152);   // 8 MB, live to k_edge
    float* sq     = ws + 4194304;           // 16384
    float* scale  = ws + 4210688;           // 128
    float* shift  = ws + 4210816;           // 128
    int*   idx    = (int*)(ws + 4210944);   // 147456 ints
    unsigned short* wf1 = (unsigned short*)(ws + 4358400);  // 32768 bf16
    unsigned short* wf2 = (unsigned short*)(ws + 4374784);  // 16384 bf16

    k_transpose<<<2048, 256, 0, stream>>>(x, featsT);
    k_prep     <<<2048, 256, 0, stream>>>(featsT, Bf, sq);
    k_prepack  <<<  24, 256, 0, stream>>>(W1, W2, wf1, wf2);
    k_knn      <<<1024, 512, 0, stream>>>(Bf, sq, idx);
    k_edge     <<<2048, 512, 0, stream>>>(Bf, idx, wf1, wf2, b1, b2, msg);
    k_bnstats  <<< 128, 256, 0, stream>>>(msg, gamma, beta, scale, shift);
    k_final    <<<2048, 256, 0, stream>>>(msg, x, scale, shift, out);
}

// Round 16
// 178.539 us; speedup vs baseline: 1.1856x; 1.1856x over previous
//
#include <hip/hip_runtime.h>

#define B_ 16
#define C_ 128
#define N_ 1024
#define K_ 9
#define NEG_SLOPE 0.2f
#define BN_EPS 1e-5f

typedef __attribute__((ext_vector_type(8))) short short8;
typedef __attribute__((ext_vector_type(4))) float f32x4;
typedef __attribute__((ext_vector_type(4))) unsigned short u16x4;

__device__ __forceinline__ unsigned short f2bf(float f) {
    union { float f; unsigned u; } v; v.f = f;
    unsigned r = v.u + 0x7fffu + ((v.u >> 16) & 1u);   // RNE
    return (unsigned short)(r >> 16);
}
__device__ __forceinline__ float bf2f(unsigned short h) {
    union { unsigned u; float f; } v; v.u = ((unsigned)h) << 16; return v.f;
}

// ------------------------------------------------- featsT[b][n][c] = x[b][c][n]
__global__ __launch_bounds__(256) void k_transpose(const float* __restrict__ x,
                                                   float* __restrict__ featsT)
{
    __shared__ float t[32][33];
    int blk = blockIdx.x;            // B * (C/32) * (N/32) = 2048
    int b = blk / 128;
    int rem = blk % 128;
    int c0 = (rem / 32) * 32;
    int n0 = (rem % 32) * 32;
    int tj = threadIdx.x & 31;
    int ti = threadIdx.x >> 5;
    #pragma unroll
    for (int s = 0; s < 32; s += 8)
        t[ti + s][tj] = x[(b * C_ + c0 + ti + s) * N_ + n0 + tj];
    __syncthreads();
    #pragma unroll
    for (int s = 0; s < 32; s += 8)
        featsT[(b * N_ + n0 + ti + s) * C_ + c0 + tj] = t[tj][ti + s];
}

// ---------------- prep: Bf (hi/lo bf16 fragment-order table) + sq (fp32)
__global__ __launch_bounds__(256) void k_prep(const float* __restrict__ featsT,
        unsigned short* __restrict__ Bf, float* __restrict__ sq)
{
    int tid = threadIdx.x;
    int lane = tid & 63, wv = tid >> 6;
    int half = lane >> 5;
    int l2 = lane & 31;
    int gp = blockIdx.x * 8 + wv * 2 + half; // global point
    int b = gp >> 10, n = gp & 1023;

    int ch0 = (l2 & 15) * 8;
    const float4* f4 = (const float4*)&featsT[gp * C_ + ch0];
    float4 v0 = f4[0], v1 = f4[1];

    u16x4 o0, o1;
    if (l2 < 16) {
        o0.x = f2bf(v0.x); o0.y = f2bf(v0.y); o0.z = f2bf(v0.z); o0.w = f2bf(v0.w);
        o1.x = f2bf(v1.x); o1.y = f2bf(v1.y); o1.z = f2bf(v1.z); o1.w = f2bf(v1.w);
    } else {
        o0.x = f2bf(v0.x - bf2f(f2bf(v0.x))); o0.y = f2bf(v0.y - bf2f(f2bf(v0.y)));
        o0.z = f2bf(v0.z - bf2f(f2bf(v0.z))); o0.w = f2bf(v0.w - bf2f(f2bf(v0.w)));
        o1.x = f2bf(v1.x - bf2f(f2bf(v1.x))); o1.y = f2bf(v1.y - bf2f(f2bf(v1.y)));
        o1.z = f2bf(v1.z - bf2f(f2bf(v1.z))); o1.w = f2bf(v1.w - bf2f(f2bf(v1.w)));
    }
    // chunk = ((b*8 + kb)*64 + tile)*64 + quad*16 + (n&15); kb 0..3 hi, 4..7 lo
    long chunk = (((long)(b * 8 + (l2 >> 2)) * 64 + (n >> 4)) << 6) + ((l2 & 3) * 16 + (n & 15));
    *(u16x4*)&Bf[chunk * 8]     = o0;
    *(u16x4*)&Bf[chunk * 8 + 4] = o1;

    float ss = v0.x*v0.x + v0.y*v0.y + v0.z*v0.z + v0.w*v0.w
             + v1.x*v1.x + v1.y*v1.y + v1.z*v1.z + v1.w*v1.w;
    #pragma unroll
    for (int off = 1; off < 16; off <<= 1)
        ss += __shfl_xor(ss, off);
    if (l2 == 0) sq[gp] = ss;
}

// --------------- MFMA KNN: 16 rows x 1024 cols; A-frags direct from Bf
// (coalesced: wave reads one contiguous 1KB chunk), r-split 2-phase keybuf,
// (512,6): no spill (R13/R14-verified).
__global__ __launch_bounds__(512, 6) void k_knn(
        const unsigned short* __restrict__ Bf, const float* __restrict__ sq,
        int* __restrict__ idxout)
{
    __shared__ unsigned keybuf[8][1028];
    __shared__ float sqn[16];

    int L = blockIdx.x;                       // 1024 = 16 b * 64 tiles
    int xcd = L & 7, slot = L >> 3;
    int b = xcd * 2 + (slot >> 6);
    int tile = slot & 63;
    int n0 = tile * 16;
    int tid = threadIdx.x;

    if (tid < 16) sqn[tid] = sq[b * N_ + n0 + tid];
    __syncthreads();

    int wv = tid >> 6, lane = tid & 63, quad = lane >> 4, cl = lane & 15;

    f32x4 acc[8];
    #pragma unroll
    for (int t = 0; t < 8; ++t) acc[t] = (f32x4){0.f, 0.f, 0.f, 0.f};

    const short8* bfp = (const short8*)Bf;
    #pragma unroll
    for (int kb = 0; kb < 4; ++kb) {
        long abase = (((long)(b * 8 + kb) * 64 + tile) << 6) + quad * 16 + cl;
        short8 afh = bfp[abase];
        short8 afl = bfp[abase + 16384];      // +4*64*64 chunks (lo table)
        long bh = (((long)(b * 8 + kb) * 64 + wv * 8) << 6) + lane;
        long bl = bh + 16384;
        #pragma unroll
        for (int t = 0; t < 8; ++t) {         // B-hi: hiA*hiB + loA*hiB
            short8 bfr = bfp[bh + t * 64];
            acc[t] = __builtin_amdgcn_mfma_f32_16x16x32_bf16(afh, bfr, acc[t], 0, 0, 0);
            acc[t] = __builtin_amdgcn_mfma_f32_16x16x32_bf16(afl, bfr, acc[t], 0, 0, 0);
        }
        #pragma unroll
        for (int t = 0; t < 8; ++t) {         // B-lo: hiA*loB
            short8 bfr = bfp[bl + t * 64];
            acc[t] = __builtin_amdgcn_mfma_f32_16x16x32_bf16(afh, bfr, acc[t], 0, 0, 0);
        }
    }

    // convert acc -> monotone u32 keys; r={0,1} staged now, r={2,3} held (16 regs)
    unsigned k0[8][2], k1[8][2];
    #pragma unroll
    for (int t = 0; t < 8; ++t) {
        int col = ((wv * 8 + t) << 4) + cl;
        float sm = sq[b * N_ + col];
        #pragma unroll
        for (int r = 0; r < 4; ++r) {
            float d2 = fmaf(-2.f, acc[t][r], sm + sqn[quad * 4 + r]);
            unsigned bits = __float_as_uint(d2);
            unsigned key = bits ^ ((unsigned)((int)bits >> 31) | 0x80000000u);
            if (r < 2) k0[t][r] = key; else k1[t][r - 2] = key;
        }
    }

    // two phases: ph=0 rows quad*4+{0,1}, ph=1 rows quad*4+{2,3}
    #pragma unroll 1
    for (int ph = 0; ph < 2; ++ph) {
        #pragma unroll
        for (int t = 0; t < 8; ++t) {
            int col = ((wv * 8 + t) << 4) + cl;
            #pragma unroll
            for (int r2 = 0; r2 < 2; ++r2)
                keybuf[quad * 2 + r2][col] = ph ? k1[t][r2] : k0[t][r2];
        }
        __syncthreads();

        int grow = ((wv >> 1) << 2) + ph * 2 + (wv & 1);
        unsigned v[16];
        #pragma unroll
        for (int j = 0; j < 16; ++j)
            v[j] = keybuf[wv][lane + (j << 6)];   // stride-1: conflict-free

        unsigned m = v[0]; int bj = 0;
        #pragma unroll
        for (int j = 1; j < 16; ++j)
            if (v[j] < m) { m = v[j]; bj = j; }   // first j wins ties = smaller col

        #pragma unroll 1
        for (int q = 0; q < K_; ++q) {
            unsigned long long my = ((unsigned long long)m << 10)
                                  | (unsigned)(lane + (bj << 6));
            unsigned long long d = my;
            #pragma unroll
            for (int off = 1; off < 64; off <<= 1) {
                unsigned long long o = __shfl_xor(d, off);
                if (o < d) d = o;
            }
            if (lane == 0)
                idxout[(b * N_ + n0 + grow) * K_ + q] = (int)((unsigned)d & 1023u);
            if (q < K_ - 1 && my == d) {           // unique winner: mask + rescan
                v[bj] = 0xFFFFFFFFu;
                m = v[0]; bj = 0;
                #pragma unroll
                for (int j = 1; j < 16; ++j)
                    if (v[j] < m) { m = v[j]; bj = j; }
            }
        }
        __syncthreads();   // all reads done before next phase overwrites keybuf
    }
}

// ----------------------- prepack W1/W2 into MFMA B-fragment order (bf16)
__global__ __launch_bounds__(256) void k_prepack(const float* __restrict__ W1,
        const float* __restrict__ W2, unsigned short* __restrict__ wf1,
        unsigned short* __restrict__ wf2)
{
    int t = blockIdx.x * 256 + threadIdx.x;       // 6144 threads
    if (t < 4096) {                               // W1: kk 0..7
        int kk = t >> 9, w = (t >> 6) & 7, lane = t & 63;
        int quad = lane >> 4, col = lane & 15;
        #pragma unroll
        for (int j = 0; j < 8; ++j)
            wf1[t * 8 + j] = f2bf(W1[(kk * 32 + quad * 8 + j) * C_ + 16 * w + col]);
    } else if (t < 6144) {                        // W2: kk 0..3
        int t2 = t - 4096;
        int kk = t2 >> 9, w = (t2 >> 6) & 7, lane = t2 & 63;
        int quad = lane >> 4, col = lane & 15;
        #pragma unroll
        for (int j = 0; j < 8; ++j)
            wf2[t2 * 8 + j] = f2bf(W2[(kk * 32 + quad * 8 + j) * C_ + 16 * w + col]);
    }
}

// ------- MFMA edge-MLP + maxpool: block = 8 points (72 edges, padded to 80 rows)
// center/diff split; h2 + cc stored bf16 -> LDS 51.3 KB -> 3 blocks/CU
// (R13-verified; R14's gather-free variant regressed: scattered A-frag loads)
__global__ __launch_bounds__(512, 6) void k_edge(const float* __restrict__ featsT,
        const int* __restrict__ idx, const unsigned short* __restrict__ wf1,
        const unsigned short* __restrict__ wf2, const float* __restrict__ b1,
        const float* __restrict__ b2, float* __restrict__ msg)
{
    // layout (bytes):
    //  [0)      diffs bf16 [80][136] (21760)   } h2b bf16 [80][136] aliases after G1b
    //  [21760)  cenb  bf16 [16][136] ( 4352)
    //  [26112)  h1    bf16 [80][136] (21760)
    //  [47872)  ccb   bf16 [16][136] ( 4352)
    __shared__ __align__(16) char smem[52224];
    unsigned short* diffs = (unsigned short*)smem;
    unsigned short* cenb  = (unsigned short*)(smem + 21760);
    unsigned short* h2b   = (unsigned short*)smem;
    unsigned short* h1    = (unsigned short*)(smem + 26112);
    unsigned short* ccb   = (unsigned short*)(smem + 47872);
    __shared__ int nb[72];

    int L = blockIdx.x;                 // 2048 = 8 xcd * 256 slots
    int xcd = L & 7, slot = L >> 3;
    int b = xcd * 2 + (slot >> 7);
    int tile = slot & 127;
    int n0 = tile * 8;
    int tid = threadIdx.x;

    if (tid < 72) nb[tid] = idx[(b * N_ + n0 + tid / 9) * K_ + tid % 9];
    __syncthreads();

    // ---- gather: 64 threads per point; halves split the 9 edges 5/4
    {
        int g = tid >> 6, j = tid & 63;
        int chunk = j & 31, ch = chunk << 2, half = j >> 5;
        const float4* fT4 = (const float4*)featsT;
        float4 cv = fT4[(b * N_ + n0 + g) * 32 + chunk];
        if (half == 0) {
            u16x4 cb; cb.x = f2bf(cv.x); cb.y = f2bf(cv.y);
            cb.z = f2bf(cv.z); cb.w = f2bf(cv.w);
            *(u16x4*)&cenb[g * 136 + ch] = cb;
        }
        int qb = half ? 5 : 0, qe = half ? 9 : 5;
        for (int q = qb; q < qe; ++q) {
            int e = g * 9 + q;
            float4 nv = fT4[(b * N_ + nb[e]) * 32 + chunk];
            u16x4 db;
            db.x = f2bf(nv.x - cv.x); db.y = f2bf(nv.y - cv.y);
            db.z = f2bf(nv.z - cv.z); db.w = f2bf(nv.w - cv.w);
            *(u16x4*)&diffs[e * 136 + ch] = db;
        }
    }
    __syncthreads();

    int wv = tid >> 6, lane = tid & 63;
    int quad = lane >> 4, cl = lane & 15;
    const short8* w1f = (const short8*)wf1;
    const short8* w2f = (const short8*)wf2;

    // ---- G1a: centers @ W1_top + b1 -> cc (bf16; rows 8..15 garbage, never read)
    {
        float b1v = b1[16 * wv + cl];
        f32x4 a = (f32x4){b1v, b1v, b1v, b1v};
        #pragma unroll
        for (int kk = 0; kk < 4; ++kk) {
            short8 af = *(const short8*)&cenb[cl * 136 + kk * 32 + quad * 8];
            short8 bf = w1f[(kk * 8 + wv) * 64 + lane];
            a = __builtin_amdgcn_mfma_f32_16x16x32_bf16(af, bf, a, 0, 0, 0);
        }
        #pragma unroll
        for (int r = 0; r < 4; ++r)
            ccb[(quad * 4 + r) * 136 + 16 * wv + cl] = f2bf(a[r]);
    }

    // ---- G1b: diffs @ W1_bot, + cc[point], leaky -> h1
    #pragma unroll
    for (int t = 0; t < 5; ++t) {
        f32x4 a = (f32x4){0.f, 0.f, 0.f, 0.f};
        #pragma unroll
        for (int kb = 0; kb < 4; ++kb) {
            short8 af = *(const short8*)&diffs[(16 * t + cl) * 136 + kb * 32 + quad * 8];
            short8 bf = w1f[((kb + 4) * 8 + wv) * 64 + lane];
            a = __builtin_amdgcn_mfma_f32_16x16x32_bf16(af, bf, a, 0, 0, 0);
        }
        #pragma unroll
        for (int r = 0; r < 4; ++r) {
            int row = 16 * t + quad * 4 + r;
            int pt = row / 9; if (pt > 7) pt = 7;
            float v = a[r] + bf2f(ccb[pt * 136 + 16 * wv + cl]);
            v = (v >= 0.f) ? v : NEG_SLOPE * v;
            h1[row * 136 + 16 * wv + cl] = f2bf(v);
        }
    }
    __syncthreads();

    // ---- GEMM2: h1 @ W2 -> h2 (bf16, aliases dead diffs)
    #pragma unroll
    for (int t = 0; t < 5; ++t) {
        f32x4 a = (f32x4){0.f, 0.f, 0.f, 0.f};
        #pragma unroll
        for (int kb = 0; kb < 4; ++kb) {
            short8 af = *(const short8*)&h1[(16 * t + cl) * 136 + kb * 32 + quad * 8];
            short8 bf = w2f[(kb * 8 + wv) * 64 + lane];
            a = __builtin_amdgcn_mfma_f32_16x16x32_bf16(af, bf, a, 0, 0, 0);
        }
        #pragma unroll
        for (int r = 0; r < 4; ++r)
            h2b[(16 * t + quad * 4 + r) * 136 + 16 * wv + cl] = f2bf(a[r]);
    }
    __syncthreads();

    // ---- maxpool over 9 edges/point + bias, write msg (B,C,N)
    int p = tid & 7, nb8 = tid >> 3;      // nb8: 0..63
    #pragma unroll
    for (int it = 0; it < 2; ++it) {
        int n = nb8 + 64 * it;
        float m = bf2f(h2b[(p * 9) * 136 + n]);
        #pragma unroll
        for (int q = 1; q < 9; ++q)
            m = fmaxf(m, bf2f(h2b[(p * 9 + q) * 136 + n]));
        msg[(b * C_ + n) * N_ + n0 + p] = m + b2[n];
    }
}

// ---------------------------------------------------- BN statistics per channel
__global__ __launch_bounds__(256) void k_bnstats(const float* __restrict__ msg,
        const float* __restrict__ gamma, const float* __restrict__ beta,
        float* __restrict__ scale, float* __restrict__ shift)
{
    int c = blockIdx.x, tid = threadIdx.x;
    float s = 0.f, ss = 0.f;
    for (int b = 0; b < B_; ++b) {
        const float* row = msg + (b * C_ + c) * N_;
        for (int j = tid; j < N_; j += 256) {
            float v = row[j];
            s += v; ss += v * v;
        }
    }
    __shared__ float rs[256], rss[256];
    rs[tid] = s; rss[tid] = ss;
    __syncthreads();
    for (int off = 128; off > 0; off >>= 1) {
        if (tid < off) { rs[tid] += rs[tid + off]; rss[tid] += rss[tid + off]; }
        __syncthreads();
    }
    if (tid == 0) {
        float mean = rs[0] / (float)(B_ * N_);
        float var = rss[0] / (float)(B_ * N_) - mean * mean;
        float inv = 1.0f / sqrtf(var + BN_EPS);
        float g = gamma[c];
        scale[c] = g * inv;
        shift[c] = beta[c] - g * inv * mean;
    }
}

// ------------------------------------------- BN apply + residual + final ReLU
__global__ __launch_bounds__(256) void k_final(const float* __restrict__ msg,
        const float* __restrict__ x, const float* __restrict__ scale,
        const float* __restrict__ shift, float* __restrict__ out)
{
    int i = blockIdx.x * 256 + threadIdx.x;
    int e = i << 2;
    int c = (e >> 10) & 127;
    float sc = scale[c], sh = shift[c];
    float4 m4 = reinterpret_cast<const float4*>(msg)[i];
    float4 x4 = reinterpret_cast<const float4*>(x)[i];
    float4 o;
    o.x = fmaxf(m4.x * sc + sh + x4.x, 0.f);
    o.y = fmaxf(m4.y * sc + sh + x4.y, 0.f);
    o.z = fmaxf(m4.z * sc + sh + x4.z, 0.f);
    o.w = fmaxf(m4.w * sc + sh + x4.w, 0.f);
    reinterpret_cast<float4*>(out)[i] = o;
}

extern "C" void kernel_launch(void* const* d_in, const int* in_sizes, int n_in,
                              void* d_out, int out_size, void* d_ws, size_t ws_size,
                              hipStream_t stream)
{
    const float* x     = (const float*)d_in[0];
    const float* W1    = (const float*)d_in[1];
    const float* b1    = (const float*)d_in[2];
    const float* W2    = (const float*)d_in[3];
    const float* b2    = (const float*)d_in[4];
    const float* gamma = (const float*)d_in[5];
    const float* beta  = (const float*)d_in[6];
    float* out = (float*)d_out;

    float* ws     = (float*)d_ws;
    float* featsT = ws;                     // 8 MB, live through k_edge
    float* msg    = ws + 2097152;           // 8 MB; Bf aliases (dead before k_edge)
    unsigned short* Bf = (unsigned short*)(ws + 2097152);
    float* sq     = ws + 4194304;           // 16384
    float* scale  = ws + 4210688;           // 128
    float* shift  = ws + 4210816;           // 128
    int*   idx    = (int*)(ws + 4210944);   // 147456 ints
    unsigned short* wf1 = (unsigned short*)(ws + 4358400);  // 32768 bf16
    unsigned short* wf2 = (unsigned short*)(ws + 4374784);  // 16384 bf16

    k_transpose<<<2048, 256, 0, stream>>>(x, featsT);
    k_prep     <<<2048, 256, 0, stream>>>(featsT, Bf, sq);
    k_prepack  <<<  24, 256, 0, stream>>>(W1, W2, wf1, wf2);
    k_knn      <<<1024, 512, 0, stream>>>(Bf, sq, idx);
    k_edge     <<<2048, 512, 0, stream>>>(featsT, idx, wf1, wf2, b1, b2, msg);
    k_bnstats  <<< 128, 256, 0, stream>>>(msg, gamma, beta, scale, shift);
    k_final    <<<2048, 256, 0, stream>>>(msg, x, scale, shift, out);
}